// Round 5
// baseline (3317.425 us; speedup 1.0000x reference)
//
#include <hip/hip_runtime.h>
#include <math.h>

#define H    1024
#define C    151
#define E    200
#define DIN  2048
#define T    32
#define B    128
#define SIXH  6144
#define FIVEH 5120
#define KTOT  2048
#define NEMB  152

typedef _Float16 f16x8 __attribute__((ext_vector_type(8)));
typedef _Float16 f16x4 __attribute__((ext_vector_type(4)));
typedef float    f32x4 __attribute__((ext_vector_type(4)));

#define MFMA16(a, b, c) __builtin_amdgcn_mfma_f32_16x16x32_f16(a, b, c, 0, 0, 0)
#define GLOAD_LDS16(g, l) __builtin_amdgcn_global_load_lds( \
    (const __attribute__((address_space(1))) unsigned int*)(g), \
    (__attribute__((address_space(3))) unsigned int*)(l), 16, 0, 0)

__device__ __forceinline__ float sigm(float x) { return 1.f / (1.f + expf(-x)); }

__device__ __forceinline__ void wait_ge(int* p, int v) {
    while (__hip_atomic_load(p, __ATOMIC_ACQUIRE, __HIP_MEMORY_SCOPE_AGENT) < v)
        __builtin_amdgcn_s_sleep(2);
}
__device__ __forceinline__ void flag_store(int* p, int v) {
    __threadfence();
    __hip_atomic_store(p, v, __ATOMIC_RELEASE, __HIP_MEMORY_SCOPE_AGENT);
}

// ---------------- X [4096][2048] fp32 -> hi/lo fp16 ----------------
__global__ void cvt_x(const float* __restrict__ X, _Float16* __restrict__ hi,
                      _Float16* __restrict__ lo) {
    size_t i = ((size_t)blockIdx.x * 256 + threadIdx.x) * 4;
    float4 v = *(const float4*)(X + i);
    f16x4 h, l;
    h.x = (_Float16)v.x; l.x = (_Float16)(v.x - (float)h.x);
    h.y = (_Float16)v.y; l.y = (_Float16)(v.y - (float)h.y);
    h.z = (_Float16)v.z; l.z = (_Float16)(v.z - (float)h.z);
    h.w = (_Float16)v.w; l.w = (_Float16)(v.w - (float)h.w);
    *(f16x4*)(hi + i) = h;
    *(f16x4*)(lo + i) = l;
}

// ---------------- W [KR][NC] fp32 -> [NC][KR] hi/lo fp16 (transposed) ----------------
template<int KR, int NC>
__global__ void cvt_wT(const float* __restrict__ W, _Float16* __restrict__ hi,
                       _Float16* __restrict__ lo) {
    __shared__ float tile[32][33];
    int n0 = blockIdx.x * 32, k0 = blockIdx.y * 32;
    int tx = threadIdx.x & 31, ty = threadIdx.x >> 5;
    #pragma unroll
    for (int i = 0; i < 4; ++i) {
        int k = ty + i * 8;
        tile[k][tx] = W[(size_t)(k0 + k) * NC + n0 + tx];
    }
    __syncthreads();
    #pragma unroll
    for (int i = 0; i < 4; ++i) {
        int n = ty + i * 8;
        float v = tile[tx][n];
        _Float16 h = (_Float16)v;
        size_t o = (size_t)(n0 + n) * KR + k0 + tx;
        hi[o] = h;
        lo[o] = (_Float16)(v - (float)h);
    }
}

// ---------------- Wo [1024][151] -> WoT [160][1024] hi/lo, zero-padded ----------
__global__ void cvt_woT(const float* __restrict__ Wo, _Float16* __restrict__ hi,
                        _Float16* __restrict__ lo) {
    int idx = blockIdx.x * 256 + threadIdx.x;
    int cc = idx >> 10, kk = idx & 1023;
    float v = (cc < C) ? Wo[(size_t)kk * C + cc] : 0.f;
    _Float16 h = (_Float16)v;
    hi[idx] = h;
    lo[idx] = (_Float16)(v - (float)h);
}

// ---------------- Etab[k][n] = sum_e embed[k][e] * Wi[DIN+e][n]  (fp32) ----------------
__global__ void etab_kernel(const float* __restrict__ embed,
                            const float* __restrict__ Wi,
                            float* __restrict__ Etab) {
    int n = blockIdx.x * 256 + threadIdx.x;
    int k = blockIdx.y;
    const float* wp = Wi + (size_t)DIN * SIXH + n;
    const float* ep = embed + k * E;
    float acc = 0.f;
    #pragma unroll 8
    for (int e = 0; e < E; ++e)
        acc = fmaf(ep[e], wp[(size_t)e * SIXH], acc);
    Etab[(size_t)k * SIXH + n] = acc;
}

// ---------------- P = X @ Wi_x + bi, fp16x3 MFMA (validated round 2) ----------------
__global__ __launch_bounds__(256) void big_gemm_mfma(
    const _Float16* __restrict__ Ahi, const _Float16* __restrict__ Alo,
    const _Float16* __restrict__ Bhi, const _Float16* __restrict__ Blo,
    const float* __restrict__ bi, float* __restrict__ P)
{
    __shared__ __align__(16) _Float16 sAh[128 * 32];
    __shared__ __align__(16) _Float16 sAl[128 * 32];
    __shared__ __align__(16) _Float16 sBh[128 * 32];
    __shared__ __align__(16) _Float16 sBl[128 * 32];
    const int tid = threadIdx.x;
    const int n0 = blockIdx.x * 128;
    const int m0 = blockIdx.y * 128;
    const int lane = tid & 63, w = tid >> 6;
    const int wm = (w >> 1) * 64, wn = (w & 1) * 64;
    const int lr = lane & 15, lq = lane >> 4;

    f32x4 acc[4][4];
    #pragma unroll
    for (int i = 0; i < 4; ++i)
        #pragma unroll
        for (int j = 0; j < 4; ++j)
            acc[i][j] = (f32x4){0.f, 0.f, 0.f, 0.f};

    const int row0 = tid >> 2;
    const int kc = tid & 3;

    for (int k0 = 0; k0 < KTOT; k0 += 32) {
        #pragma unroll
        for (int i = 0; i < 2; ++i) {
            int row = row0 + i * 64;
            size_t ga = (size_t)(m0 + row) * KTOT + k0 + kc * 8;
            size_t gb = (size_t)(n0 + row) * KTOT + k0 + kc * 8;
            int loff = (i * 256 + tid) * 8;
            GLOAD_LDS16(Ahi + ga, sAh + loff);
            GLOAD_LDS16(Alo + ga, sAl + loff);
            GLOAD_LDS16(Bhi + gb, sBh + loff);
            GLOAD_LDS16(Blo + gb, sBl + loff);
        }
        __syncthreads();
        f16x8 ah[4], al[4], bh[4], bl[4];
        #pragma unroll
        for (int i = 0; i < 4; ++i) {
            ah[i] = *(const f16x8*)&sAh[(wm + i * 16 + lr) * 32 + lq * 8];
            al[i] = *(const f16x8*)&sAl[(wm + i * 16 + lr) * 32 + lq * 8];
            bh[i] = *(const f16x8*)&sBh[(wn + i * 16 + lr) * 32 + lq * 8];
            bl[i] = *(const f16x8*)&sBl[(wn + i * 16 + lr) * 32 + lq * 8];
        }
        #pragma unroll
        for (int i = 0; i < 4; ++i)
            #pragma unroll
            for (int j = 0; j < 4; ++j) {
                acc[i][j] = MFMA16(ah[i], bh[j], acc[i][j]);
                acc[i][j] = MFMA16(ah[i], bl[j], acc[i][j]);
                acc[i][j] = MFMA16(al[i], bh[j], acc[i][j]);
            }
        __syncthreads();
    }
    #pragma unroll
    for (int i = 0; i < 4; ++i)
        #pragma unroll
        for (int j = 0; j < 4; ++j) {
            int gcol = n0 + wn + j * 16 + lr;
            float bv = bi[gcol];
            #pragma unroll
            for (int r = 0; r < 4; ++r) {
                int grow = m0 + wm + i * 16 + lq * 4 + r;
                P[(size_t)grow * SIXH + gcol] = acc[i][j][r] + bv;
            }
        }
}

// ---------------- shared pred step: 16 batches x 160 cls, fp16x4 MFMA ----------------
__device__ __forceinline__ void pred_step(
    int t, int m0,
    const _Float16* __restrict__ hhi, const _Float16* __restrict__ hlo,
    const _Float16* __restrict__ WoThi, const _Float16* __restrict__ WoTlo,
    const float* __restrict__ bo, const int* __restrict__ labels,
    float* __restrict__ dists, float* __restrict__ comms, int* __restrict__ eidx,
    float (*smax)[10], int (*simax)[10])
{
    const int tid = threadIdx.x;
    const int lane = tid & 63, w = tid >> 6;
    const int lr = lane & 15, lq = lane >> 4;
    #pragma unroll
    for (int s = 0; s < 3; ++s) {
        int nt = w + s * 4;
        if (nt < 10) {
            f32x4 p0 = (f32x4){0.f, 0.f, 0.f, 0.f};
            f32x4 p1 = (f32x4){0.f, 0.f, 0.f, 0.f};
            const _Float16* ha = hhi + (size_t)(m0 + lr) * H + lq * 8;
            const _Float16* la = hlo + (size_t)(m0 + lr) * H + lq * 8;
            const _Float16* hb = WoThi + (size_t)(nt * 16 + lr) * H + lq * 8;
            const _Float16* lb = WoTlo + (size_t)(nt * 16 + lr) * H + lq * 8;
            for (int k0 = 0; k0 < H; k0 += 64) {
                f16x8 ah0 = *(const f16x8*)(ha + k0);
                f16x8 al0 = *(const f16x8*)(la + k0);
                f16x8 bh0 = *(const f16x8*)(hb + k0);
                f16x8 bl0 = *(const f16x8*)(lb + k0);
                f16x8 ah1 = *(const f16x8*)(ha + k0 + 32);
                f16x8 al1 = *(const f16x8*)(la + k0 + 32);
                f16x8 bh1 = *(const f16x8*)(hb + k0 + 32);
                f16x8 bl1 = *(const f16x8*)(lb + k0 + 32);
                p0 = MFMA16(ah0, bh0, p0); p0 = MFMA16(ah0, bl0, p0);
                p0 = MFMA16(al0, bh0, p0); p0 = MFMA16(al0, bl0, p0);
                p1 = MFMA16(ah1, bh1, p1); p1 = MFMA16(ah1, bl1, p1);
                p1 = MFMA16(al1, bh1, p1); p1 = MFMA16(al1, bl1, p1);
            }
            int cls = nt * 16 + lr;
            float bv = (cls < C) ? bo[cls] : 0.f;
            float rv[4];
            #pragma unroll
            for (int r = 0; r < 4; ++r) {
                float v = p0[r] + p1[r] + bv;
                if (cls < C)
                    dists[((size_t)t * B + m0 + lq * 4 + r) * C + cls] = v;
                rv[r] = (cls >= 1 && cls < C) ? v : -3e38f;
            }
            #pragma unroll
            for (int r = 0; r < 4; ++r) {
                float mv = rv[r]; int mi = cls;
                #pragma unroll
                for (int m = 1; m <= 8; m <<= 1) {
                    float ov = __shfl_xor(mv, m, 64);
                    int   oi = __shfl_xor(mi, m, 64);
                    if (ov > mv || (ov == mv && oi < mi)) { mv = ov; mi = oi; }
                }
                if (lr == 0) { smax[lq * 4 + r][nt] = mv; simax[lq * 4 + r][nt] = mi; }
            }
        }
    }
    __syncthreads();
    if (tid < 16) {
        float bv = -3e38f; int bx = 1 << 20;
        #pragma unroll
        for (int p = 0; p < 10; ++p) {
            float v = smax[tid][p]; int ix = simax[tid][p];
            if (v > bv || (v == bv && ix < bx)) { bv = v; bx = ix; }
        }
        int lt = labels[t * B + m0 + tid];
        int cm = (lt == 0) ? bx : lt;
        comms[(size_t)t * B + m0 + tid] = (float)cm;
        eidx[m0 + tid] = cm + 1;
    }
    __syncthreads();
}

// ================= persistent loop with point-to-point flag sync =================
// 136 blocks x 256. bids 0..127: Ws-GEMM halves (nt=bid>>1, kh=bid&1) + gate (kh==0).
// bids 128..135: pred blocks. h/eidx double-buffered by step parity; per-step flags.
struct LoopArgs {
    const _Float16 *WsThi, *WsTlo, *WoThi, *WoTlo;
    const float *P, *Etab, *bs, *bo;
    const int *labels;
    _Float16 *hhi0, *hlo0, *hhi1, *hlo1;
    float *psPart;
    int *eidx0, *eidx1;
    int *hReady, *eReady, *psReady;   // [T], [T], [T*64] — zeroed before launch
    float *dists, *comms;
};

__global__ __launch_bounds__(256) void loop_flags(LoopArgs a) {
    const int bid = blockIdx.x;
    const int tid = threadIdx.x;
    const int lane = tid & 63, w = tid >> 6;
    const int lr = lane & 15, lq = lane >> 4;

    __shared__ __align__(16) _Float16 sAh[128 * 128];   // 32 KB
    __shared__ __align__(16) _Float16 sAl[128 * 128];   // 32 KB
    __shared__ __align__(16) _Float16 sBh[80 * 128];    // 20 KB
    __shared__ __align__(16) _Float16 sBl[80 * 128];    // 20 KB
    __shared__ float smax[16][10];
    __shared__ int   simax[16][10];

    const bool isG = bid < 128;
    const int nt = bid >> 1, kh = bid & 1, n0 = nt * 16;
    const int m0p = (bid - 128) * 16;

    float c_reg[2][4] = {{0.f,0.f,0.f,0.f},{0.f,0.f,0.f,0.f}};

    for (int t = 0; t < T; ++t) {
        _Float16* curHhi = (t & 1) ? a.hhi1 : a.hhi0;
        _Float16* curHlo = (t & 1) ? a.hlo1 : a.hlo0;
        const _Float16* prvHhi = (t & 1) ? a.hhi0 : a.hhi1;   // h(t-1)
        const _Float16* prvHlo = (t & 1) ? a.hlo0 : a.hlo1;

        if (isG) {
            f32x4 acc[2][5];
            #pragma unroll
            for (int i = 0; i < 2; ++i)
                #pragma unroll
                for (int g = 0; g < 5; ++g)
                    acc[i][g] = (f32x4){0.f, 0.f, 0.f, 0.f};

            if (t >= 1) {
                if (tid == 0) wait_ge(&a.hReady[t - 1], 64);
                __syncthreads();
                const int kbase = kh * 512;
                for (int it = 0; it < 4; ++it) {
                    const int k0 = kbase + it * 128;
                    #pragma unroll
                    for (int i = 0; i < 8; ++i) {
                        int s = i * 256 + tid;
                        int row = s >> 4, kc = s & 15;
                        size_t ga = (size_t)row * H + k0 + kc * 8;
                        GLOAD_LDS16(prvHhi + ga, sAh + s * 8);
                        GLOAD_LDS16(prvHlo + ga, sAl + s * 8);
                    }
                    #pragma unroll
                    for (int i = 0; i < 5; ++i) {
                        int s = i * 256 + tid;
                        int brow = s >> 4, kc = s & 15;
                        size_t gb = (size_t)((brow >> 4) * H + n0 + (brow & 15)) * H
                                    + k0 + kc * 8;
                        GLOAD_LDS16(a.WsThi + gb, sBh + s * 8);
                        GLOAD_LDS16(a.WsTlo + gb, sBl + s * 8);
                    }
                    __syncthreads();
                    #pragma unroll
                    for (int kq = 0; kq < 4; ++kq) {
                        f16x8 ah[2], al[2];
                        #pragma unroll
                        for (int i = 0; i < 2; ++i) {
                            ah[i] = *(const f16x8*)&sAh[((w * 2 + i) * 16 + lr) * 128 + kq * 32 + lq * 8];
                            al[i] = *(const f16x8*)&sAl[((w * 2 + i) * 16 + lr) * 128 + kq * 32 + lq * 8];
                        }
                        #pragma unroll
                        for (int g = 0; g < 5; ++g) {
                            f16x8 bh = *(const f16x8*)&sBh[(g * 16 + lr) * 128 + kq * 32 + lq * 8];
                            f16x8 bl = *(const f16x8*)&sBl[(g * 16 + lr) * 128 + kq * 32 + lq * 8];
                            #pragma unroll
                            for (int i = 0; i < 2; ++i) {
                                acc[i][g] = MFMA16(ah[i], bh, acc[i][g]);
                                acc[i][g] = MFMA16(ah[i], bl, acc[i][g]);
                                acc[i][g] = MFMA16(al[i], bh, acc[i][g]);
                            }
                        }
                    }
                    __syncthreads();
                }
            }

            if (kh == 1) {
                if (t >= 1) {
                    #pragma unroll
                    for (int i = 0; i < 2; ++i)
                        #pragma unroll
                        for (int g = 0; g < 5; ++g)
                            #pragma unroll
                            for (int r = 0; r < 4; ++r) {
                                int bb = (w * 2 + i) * 16 + lq * 4 + r;
                                a.psPart[((size_t)nt * 128 + bb) * 80 + g * 16 + lr] = acc[i][g][r];
                            }
                    __syncthreads();
                    if (tid == 0) flag_store(&a.psReady[t * 64 + nt], 1);
                }
            } else {
                if (t >= 1) {
                    if (tid == 0) {
                        wait_ge(&a.psReady[t * 64 + nt], 1);
                        wait_ge(&a.eReady[t - 1], 8);
                    }
                    __syncthreads();
                }
                const int* peidx = (t & 1) ? a.eidx0 : a.eidx1;   // eidx(t-1)
                #pragma unroll
                for (int i = 0; i < 2; ++i)
                    #pragma unroll
                    for (int r = 0; r < 4; ++r) {
                        int bb = (w * 2 + i) * 16 + lq * 4 + r;
                        int j = n0 + lr;
                        int e = (t >= 1) ? peidx[bb] : 0;
                        size_t pbase  = ((size_t)t * B + bb) * SIXH + j;
                        size_t ebase  = (size_t)e * SIXH + j;
                        size_t ppbase = ((size_t)nt * 128 + bb) * 80 + lr;
                        float gv[5];
                        #pragma unroll
                        for (int g = 0; g < 5; ++g) {
                            float part = (t >= 1) ? a.psPart[ppbase + g * 16] : 0.f;
                            gv[g] = acc[i][g][r] + part + a.P[pbase + g * 1024]
                                    + a.Etab[ebase + g * 1024] + a.bs[g * 1024 + j];
                        }
                        float p5 = a.P[pbase + 5 * 1024] + a.Etab[ebase + 5 * 1024];
                        float ig  = sigm(gv[0]);
                        float fg  = sigm(gv[1]);
                        float mi_ = tanhf(gv[2]);
                        float og  = sigm(gv[3]);
                        float hw  = sigm(gv[4]);
                        float cn  = ig * mi_ + fg * c_reg[i][r];
                        float out = og * tanhf(cn);
                        float hn  = hw * out + (1.f - hw) * p5;
                        c_reg[i][r] = cn;
                        _Float16 hh = (_Float16)hn;
                        curHhi[(size_t)bb * H + j] = hh;
                        curHlo[(size_t)bb * H + j] = (_Float16)(hn - (float)hh);
                    }
                __syncthreads();
                if (tid == 0) {
                    __threadfence();
                    atomicAdd(&a.hReady[t], 1);
                }
            }
        } else {
            // ---------------- pred block ----------------
            if (tid == 0) wait_ge(&a.hReady[t], 64);
            __syncthreads();
            int* ceidx = (t & 1) ? a.eidx1 : a.eidx0;   // eidx(t)
            pred_step(t, m0p, curHhi, curHlo, a.WoThi, a.WoTlo, a.bo, a.labels,
                      a.dists, a.comms, ceidx, smax, simax);
            if (tid == 0) {
                __threadfence();
                atomicAdd(&a.eReady[t], 1);
            }
        }
    }
}

// ================= fallback path: 2 dispatches per step (validated structure) =========
__global__ __launch_bounds__(256) void psgate_kernel(
    const _Float16* __restrict__ hPhi, const _Float16* __restrict__ hPlo,
    _Float16* __restrict__ hOhi, _Float16* __restrict__ hOlo,
    const _Float16* __restrict__ WsThi, const _Float16* __restrict__ WsTlo,
    const float* __restrict__ P, const float* __restrict__ Etab,
    const float* __restrict__ bs, const int* __restrict__ eidx,
    float* __restrict__ c, int t)
{
    const int tid = threadIdx.x;
    const int lane = tid & 63, w = tid >> 6;
    const int lr = lane & 15, lq = lane >> 4;
    const int nt = blockIdx.x;
    const int n0 = nt * 16;

    __shared__ __align__(16) _Float16 sAh[128 * 32];
    __shared__ __align__(16) _Float16 sAl[128 * 32];
    __shared__ __align__(16) _Float16 sBh[80 * 32];
    __shared__ __align__(16) _Float16 sBl[80 * 32];

    f32x4 acc[2][5];
    #pragma unroll
    for (int i = 0; i < 2; ++i)
        #pragma unroll
        for (int g = 0; g < 5; ++g)
            acc[i][g] = (f32x4){0.f, 0.f, 0.f, 0.f};

    if (t > 0) {
        for (int k0 = 0; k0 < H; k0 += 32) {
            #pragma unroll
            for (int ii = 0; ii < 2; ++ii) {
                int s = ii * 256 + tid;
                int row = s >> 2, kc = s & 3;
                size_t ga = (size_t)row * H + k0 + kc * 8;
                GLOAD_LDS16(hPhi + ga, sAh + s * 8);
                GLOAD_LDS16(hPlo + ga, sAl + s * 8);
            }
            {
                int s = tid;
                int brow = s >> 2, kc = s & 3;
                size_t gb = (size_t)((brow >> 4) * H + n0 + (brow & 15)) * H + k0 + kc * 8;
                GLOAD_LDS16(WsThi + gb, sBh + s * 8);
                GLOAD_LDS16(WsTlo + gb, sBl + s * 8);
            }
            if (tid < 64) {
                int s = 256 + tid;
                int brow = s >> 2, kc = s & 3;
                size_t gb = (size_t)((brow >> 4) * H + n0 + (brow & 15)) * H + k0 + kc * 8;
                GLOAD_LDS16(WsThi + gb, sBh + s * 8);
                GLOAD_LDS16(WsTlo + gb, sBl + s * 8);
            }
            __syncthreads();
            f16x8 ah[2], al[2];
            #pragma unroll
            for (int i = 0; i < 2; ++i) {
                ah[i] = *(const f16x8*)&sAh[((w * 2 + i) * 16 + lr) * 32 + lq * 8];
                al[i] = *(const f16x8*)&sAl[((w * 2 + i) * 16 + lr) * 32 + lq * 8];
            }
            #pragma unroll
            for (int g = 0; g < 5; ++g) {
                f16x8 bh = *(const f16x8*)&sBh[(g * 16 + lr) * 32 + lq * 8];
                f16x8 bl = *(const f16x8*)&sBl[(g * 16 + lr) * 32 + lq * 8];
                #pragma unroll
                for (int i = 0; i < 2; ++i) {
                    acc[i][g] = MFMA16(ah[i], bh, acc[i][g]);
                    acc[i][g] = MFMA16(ah[i], bl, acc[i][g]);
                    acc[i][g] = MFMA16(al[i], bh, acc[i][g]);
                }
            }
            __syncthreads();
        }
    }

    #pragma unroll
    for (int i = 0; i < 2; ++i)
        #pragma unroll
        for (int r = 0; r < 4; ++r) {
            int bb = (w * 2 + i) * 16 + lq * 4 + r;
            int j = n0 + lr;
            int e = (t > 0) ? eidx[bb] : 0;
            size_t pbase = ((size_t)t * B + bb) * SIXH + j;
            size_t ebase = (size_t)e * SIXH + j;
            float gv[5];
            #pragma unroll
            for (int g = 0; g < 5; ++g)
                gv[g] = acc[i][g][r] + P[pbase + g * 1024]
                        + Etab[ebase + g * 1024] + bs[g * 1024 + j];
            float p5 = P[pbase + 5 * 1024] + Etab[ebase + 5 * 1024];
            float ig  = sigm(gv[0]);
            float fg  = sigm(gv[1]);
            float mi_ = tanhf(gv[2]);
            float og  = sigm(gv[3]);
            float hw  = sigm(gv[4]);
            float cv  = (t > 0) ? c[(size_t)bb * H + j] : 0.f;
            float cn  = ig * mi_ + fg * cv;
            float out = og * tanhf(cn);
            float hn  = hw * out + (1.f - hw) * p5;
            c[(size_t)bb * H + j] = cn;
            _Float16 hh = (_Float16)hn;
            hOhi[(size_t)bb * H + j] = hh;
            hOlo[(size_t)bb * H + j] = (_Float16)(hn - (float)hh);
        }
}

__global__ __launch_bounds__(256) void pred_kernel8(
    const _Float16* __restrict__ hhi, const _Float16* __restrict__ hlo,
    const _Float16* __restrict__ WoThi, const _Float16* __restrict__ WoTlo,
    const float* __restrict__ bo, const int* __restrict__ labels,
    float* __restrict__ dists, float* __restrict__ comms,
    int* __restrict__ eidx, int t)
{
    __shared__ float smax[16][10];
    __shared__ int   simax[16][10];
    pred_step(t, blockIdx.x * 16, hhi, hlo, WoThi, WoTlo, bo, labels,
              dists, comms, eidx, smax, simax);
}

extern "C" void kernel_launch(void* const* d_in, const int* in_sizes, int n_in,
                              void* d_out, int out_size, void* d_ws, size_t ws_size,
                              hipStream_t stream) {
    const float* X      = (const float*)d_in[0];
    const int*   labels = (const int*)  d_in[1];
    const float* embed  = (const float*)d_in[2];
    const float* Wi     = (const float*)d_in[3];
    const float* bi     = (const float*)d_in[4];
    const float* Ws     = (const float*)d_in[5];
    const float* bs     = (const float*)d_in[6];
    const float* Wo     = (const float*)d_in[7];
    const float* bo     = (const float*)d_in[8];

    char* w = (char*)d_ws;
    float* P        = (float*)w;    w += (size_t)T * B * SIXH * 4;      // 100.7 MB
    float* Etab     = (float*)w;    w += (size_t)NEMB * SIXH * 4;       //   3.7 MB
    _Float16* Xhi   = (_Float16*)w; w += (size_t)T * B * KTOT * 2;      //  16.8 MB
    _Float16* Xlo   = (_Float16*)w; w += (size_t)T * B * KTOT * 2;      //  16.8 MB
    char* overlay   = w;
    _Float16* WiThi = (_Float16*)w; w += (size_t)SIXH * KTOT * 2;       //  25.2 MB
    _Float16* WiTlo = (_Float16*)w; w += (size_t)SIXH * KTOT * 2;       //  25.2 MB

    // overlay region (live only after big_gemm; ~28 MB < 50.3 MB)
    char* r = overlay;
    _Float16* WsThi = (_Float16*)r; r += (size_t)FIVEH * H * 2;
    _Float16* WsTlo = (_Float16*)r; r += (size_t)FIVEH * H * 2;
    _Float16* WoThi = (_Float16*)r; r += (size_t)160 * H * 2;
    _Float16* WoTlo = (_Float16*)r; r += (size_t)160 * H * 2;
    _Float16* hhi0  = (_Float16*)r; r += (size_t)B * H * 2;
    _Float16* hlo0  = (_Float16*)r; r += (size_t)B * H * 2;
    _Float16* hhi1  = (_Float16*)r; r += (size_t)B * H * 2;
    _Float16* hlo1  = (_Float16*)r; r += (size_t)B * H * 2;
    float* cArr     = (float*)r;    r += (size_t)B * H * 4;
    float* psPart   = (float*)r;    r += (size_t)64 * 128 * 80 * 4;
    int*   eidx0    = (int*)r;      r += 512;
    int*   eidx1    = (int*)r;      r += 512;
    char*  flagBase = r;
    int*   hReady   = (int*)r;      r += T * 4;
    int*   eReady   = (int*)r;      r += T * 4;
    int*   psReady  = (int*)r;      r += T * 64 * 4;
    size_t flagBytes = (size_t)(T + T + T * 64) * 4;

    float* dists = (float*)d_out;
    float* comms = dists + (size_t)T * B * C;

    cvt_x<<<(T * B * KTOT) / (256 * 4), 256, 0, stream>>>(X, Xhi, Xlo);
    cvt_wT<KTOT, SIXH><<<dim3(SIXH / 32, KTOT / 32), 256, 0, stream>>>(Wi, WiThi, WiTlo);
    etab_kernel<<<dim3(SIXH / 256, NEMB), 256, 0, stream>>>(embed, Wi, Etab);
    big_gemm_mfma<<<dim3(SIXH / 128, (T * B) / 128), 256, 0, stream>>>(Xhi, Xlo, WiThi, WiTlo, bi, P);
    cvt_wT<H, FIVEH><<<dim3(FIVEH / 32, H / 32), 256, 0, stream>>>(Ws, WsThi, WsTlo);
    cvt_woT<<<(160 * H) / 256, 256, 0, stream>>>(Wo, WoThi, WoTlo);

    bool launched = false;
    int dev = 0;
    if (hipGetDevice(&dev) == hipSuccess) {
        int coopAttr = 0, numCU = 0, occ = 0;
        hipDeviceGetAttribute(&coopAttr, hipDeviceAttributeCooperativeLaunch, dev);
        hipDeviceGetAttribute(&numCU, hipDeviceAttributeMultiprocessorCount, dev);
        hipOccupancyMaxActiveBlocksPerMultiprocessor(&occ, (const void*)loop_flags, 256, 0);
        if (coopAttr && (long)occ * numCU >= 136) {
            hipMemsetAsync(flagBase, 0, flagBytes, stream);
            LoopArgs la;
            la.WsThi = WsThi; la.WsTlo = WsTlo; la.WoThi = WoThi; la.WoTlo = WoTlo;
            la.P = P; la.Etab = Etab; la.bs = bs; la.bo = bo; la.labels = labels;
            la.hhi0 = hhi0; la.hlo0 = hlo0; la.hhi1 = hhi1; la.hlo1 = hlo1;
            la.psPart = psPart; la.eidx0 = eidx0; la.eidx1 = eidx1;
            la.hReady = hReady; la.eReady = eReady; la.psReady = psReady;
            la.dists = dists; la.comms = comms;
            void* args[] = { (void*)&la };
            launched = hipLaunchCooperativeKernel((void*)loop_flags, dim3(136), dim3(256),
                                                  args, 0, stream) == hipSuccess;
        }
    }
    if (!launched) {
        for (int t = 0; t < T; ++t) {
            _Float16* rdHi = (t & 1) ? hhi0 : hhi1;
            _Float16* rdLo = (t & 1) ? hlo0 : hlo1;
            _Float16* wrHi = (t & 1) ? hhi1 : hhi0;
            _Float16* wrLo = (t & 1) ? hlo1 : hlo0;
            psgate_kernel<<<64, 256, 0, stream>>>(rdHi, rdLo, wrHi, wrLo,
                                                  WsThi, WsTlo, P, Etab, bs, eidx0, cArr, t);
            pred_kernel8<<<8, 256, 0, stream>>>(wrHi, wrLo, WoThi, WoTlo, bo, labels,
                                                dists, comms, eidx0, t);
        }
    }
}

// Round 6
// 2795.202 us; speedup vs baseline: 1.1868x; 1.1868x over previous
//
#include <hip/hip_runtime.h>
#include <math.h>

#define H    1024
#define C    151
#define E    200
#define DIN  2048
#define T    32
#define B    128
#define SIXH  6144
#define FIVEH 5120
#define KTOT  2048
#define NEMB  152

typedef _Float16 f16x8 __attribute__((ext_vector_type(8)));
typedef _Float16 f16x4 __attribute__((ext_vector_type(4)));
typedef float    f32x4 __attribute__((ext_vector_type(4)));

#define MFMA16(a, b, c) __builtin_amdgcn_mfma_f32_16x16x32_f16(a, b, c, 0, 0, 0)
#define GLOAD_LDS16(g, l) __builtin_amdgcn_global_load_lds( \
    (const __attribute__((address_space(1))) unsigned int*)(g), \
    (__attribute__((address_space(3))) unsigned int*)(l), 16, 0, 0)

__device__ __forceinline__ float sigm(float x) { return 1.f / (1.f + expf(-x)); }

__device__ __forceinline__ void wait_ge(int* p, int v) {
    while (__hip_atomic_load(p, __ATOMIC_ACQUIRE, __HIP_MEMORY_SCOPE_AGENT) < v)
        __builtin_amdgcn_s_sleep(8);
}

// ---------------- X [4096][2048] fp32 -> hi/lo fp16 ----------------
__global__ void cvt_x(const float* __restrict__ X, _Float16* __restrict__ hi,
                      _Float16* __restrict__ lo) {
    size_t i = ((size_t)blockIdx.x * 256 + threadIdx.x) * 4;
    float4 v = *(const float4*)(X + i);
    f16x4 h, l;
    h.x = (_Float16)v.x; l.x = (_Float16)(v.x - (float)h.x);
    h.y = (_Float16)v.y; l.y = (_Float16)(v.y - (float)h.y);
    h.z = (_Float16)v.z; l.z = (_Float16)(v.z - (float)h.z);
    h.w = (_Float16)v.w; l.w = (_Float16)(v.w - (float)h.w);
    *(f16x4*)(hi + i) = h;
    *(f16x4*)(lo + i) = l;
}

// ---------------- W [KR][NC] fp32 -> [NC][KR] hi/lo fp16 (transposed) ----------------
template<int KR, int NC>
__global__ void cvt_wT(const float* __restrict__ W, _Float16* __restrict__ hi,
                       _Float16* __restrict__ lo) {
    __shared__ float tile[32][33];
    int n0 = blockIdx.x * 32, k0 = blockIdx.y * 32;
    int tx = threadIdx.x & 31, ty = threadIdx.x >> 5;
    #pragma unroll
    for (int i = 0; i < 4; ++i) {
        int k = ty + i * 8;
        tile[k][tx] = W[(size_t)(k0 + k) * NC + n0 + tx];
    }
    __syncthreads();
    #pragma unroll
    for (int i = 0; i < 4; ++i) {
        int n = ty + i * 8;
        float v = tile[tx][n];
        _Float16 h = (_Float16)v;
        size_t o = (size_t)(n0 + n) * KR + k0 + tx;
        hi[o] = h;
        lo[o] = (_Float16)(v - (float)h);
    }
}

// ---------------- Wo [1024][151] -> WoT [160][1024] hi/lo, zero-padded ----------
__global__ void cvt_woT(const float* __restrict__ Wo, _Float16* __restrict__ hi,
                        _Float16* __restrict__ lo) {
    int idx = blockIdx.x * 256 + threadIdx.x;
    int cc = idx >> 10, kk = idx & 1023;
    float v = (cc < C) ? Wo[(size_t)kk * C + cc] : 0.f;
    _Float16 h = (_Float16)v;
    hi[idx] = h;
    lo[idx] = (_Float16)(v - (float)h);
}

// ---------------- Etab[k][n] = sum_e embed[k][e] * Wi[DIN+e][n]  (fp32) ----------------
__global__ void etab_kernel(const float* __restrict__ embed,
                            const float* __restrict__ Wi,
                            float* __restrict__ Etab) {
    int n = blockIdx.x * 256 + threadIdx.x;
    int k = blockIdx.y;
    const float* wp = Wi + (size_t)DIN * SIXH + n;
    const float* ep = embed + k * E;
    float acc = 0.f;
    #pragma unroll 8
    for (int e = 0; e < E; ++e)
        acc = fmaf(ep[e], wp[(size_t)e * SIXH], acc);
    Etab[(size_t)k * SIXH + n] = acc;
}

// ---------------- P = X @ Wi_x + bi, fp16x3 MFMA (validated round 2) ----------------
__global__ __launch_bounds__(256) void big_gemm_mfma(
    const _Float16* __restrict__ Ahi, const _Float16* __restrict__ Alo,
    const _Float16* __restrict__ Bhi, const _Float16* __restrict__ Blo,
    const float* __restrict__ bi, float* __restrict__ P)
{
    __shared__ __align__(16) _Float16 sAh[128 * 32];
    __shared__ __align__(16) _Float16 sAl[128 * 32];
    __shared__ __align__(16) _Float16 sBh[128 * 32];
    __shared__ __align__(16) _Float16 sBl[128 * 32];
    const int tid = threadIdx.x;
    const int n0 = blockIdx.x * 128;
    const int m0 = blockIdx.y * 128;
    const int lane = tid & 63, w = tid >> 6;
    const int wm = (w >> 1) * 64, wn = (w & 1) * 64;
    const int lr = lane & 15, lq = lane >> 4;

    f32x4 acc[4][4];
    #pragma unroll
    for (int i = 0; i < 4; ++i)
        #pragma unroll
        for (int j = 0; j < 4; ++j)
            acc[i][j] = (f32x4){0.f, 0.f, 0.f, 0.f};

    const int row0 = tid >> 2;
    const int kc = tid & 3;

    for (int k0 = 0; k0 < KTOT; k0 += 32) {
        #pragma unroll
        for (int i = 0; i < 2; ++i) {
            int row = row0 + i * 64;
            size_t ga = (size_t)(m0 + row) * KTOT + k0 + kc * 8;
            size_t gb = (size_t)(n0 + row) * KTOT + k0 + kc * 8;
            int loff = (i * 256 + tid) * 8;
            GLOAD_LDS16(Ahi + ga, sAh + loff);
            GLOAD_LDS16(Alo + ga, sAl + loff);
            GLOAD_LDS16(Bhi + gb, sBh + loff);
            GLOAD_LDS16(Blo + gb, sBl + loff);
        }
        __syncthreads();
        f16x8 ah[4], al[4], bh[4], bl[4];
        #pragma unroll
        for (int i = 0; i < 4; ++i) {
            ah[i] = *(const f16x8*)&sAh[(wm + i * 16 + lr) * 32 + lq * 8];
            al[i] = *(const f16x8*)&sAl[(wm + i * 16 + lr) * 32 + lq * 8];
            bh[i] = *(const f16x8*)&sBh[(wn + i * 16 + lr) * 32 + lq * 8];
            bl[i] = *(const f16x8*)&sBl[(wn + i * 16 + lr) * 32 + lq * 8];
        }
        #pragma unroll
        for (int i = 0; i < 4; ++i)
            #pragma unroll
            for (int j = 0; j < 4; ++j) {
                acc[i][j] = MFMA16(ah[i], bh[j], acc[i][j]);
                acc[i][j] = MFMA16(ah[i], bl[j], acc[i][j]);
                acc[i][j] = MFMA16(al[i], bh[j], acc[i][j]);
            }
        __syncthreads();
    }
    #pragma unroll
    for (int i = 0; i < 4; ++i)
        #pragma unroll
        for (int j = 0; j < 4; ++j) {
            int gcol = n0 + wn + j * 16 + lr;
            float bv = bi[gcol];
            #pragma unroll
            for (int r = 0; r < 4; ++r) {
                int grow = m0 + wm + i * 16 + lq * 4 + r;
                P[(size_t)grow * SIXH + gcol] = acc[i][j][r] + bv;
            }
        }
}

// ---------------- pred step: 16 batches x 160 cls, fp16x4 MFMA (validated r4/r5) ------
__device__ __forceinline__ void pred_step(
    int t, int m0,
    const _Float16* __restrict__ hhi, const _Float16* __restrict__ hlo,
    const _Float16* __restrict__ WoThi, const _Float16* __restrict__ WoTlo,
    const float* __restrict__ bo, const int* __restrict__ labels,
    float* __restrict__ dists, float* __restrict__ comms, int* __restrict__ eidx,
    float (*smax)[10], int (*simax)[10])
{
    const int tid = threadIdx.x;
    const int lane = tid & 63, w = tid >> 6;
    const int lr = lane & 15, lq = lane >> 4;
    #pragma unroll
    for (int s = 0; s < 3; ++s) {
        int nt = w + s * 4;
        if (nt < 10) {
            f32x4 p0 = (f32x4){0.f, 0.f, 0.f, 0.f};
            f32x4 p1 = (f32x4){0.f, 0.f, 0.f, 0.f};
            const _Float16* ha = hhi + (size_t)(m0 + lr) * H + lq * 8;
            const _Float16* la = hlo + (size_t)(m0 + lr) * H + lq * 8;
            const _Float16* hb = WoThi + (size_t)(nt * 16 + lr) * H + lq * 8;
            const _Float16* lb = WoTlo + (size_t)(nt * 16 + lr) * H + lq * 8;
            for (int k0 = 0; k0 < H; k0 += 64) {
                f16x8 ah0 = *(const f16x8*)(ha + k0);
                f16x8 al0 = *(const f16x8*)(la + k0);
                f16x8 bh0 = *(const f16x8*)(hb + k0);
                f16x8 bl0 = *(const f16x8*)(lb + k0);
                f16x8 ah1 = *(const f16x8*)(ha + k0 + 32);
                f16x8 al1 = *(const f16x8*)(la + k0 + 32);
                f16x8 bh1 = *(const f16x8*)(hb + k0 + 32);
                f16x8 bl1 = *(const f16x8*)(lb + k0 + 32);
                p0 = MFMA16(ah0, bh0, p0); p0 = MFMA16(ah0, bl0, p0);
                p0 = MFMA16(al0, bh0, p0); p0 = MFMA16(al0, bl0, p0);
                p1 = MFMA16(ah1, bh1, p1); p1 = MFMA16(ah1, bl1, p1);
                p1 = MFMA16(al1, bh1, p1); p1 = MFMA16(al1, bl1, p1);
            }
            int cls = nt * 16 + lr;
            float bv = (cls < C) ? bo[cls] : 0.f;
            float rv[4];
            #pragma unroll
            for (int r = 0; r < 4; ++r) {
                float v = p0[r] + p1[r] + bv;
                if (cls < C)
                    dists[((size_t)t * B + m0 + lq * 4 + r) * C + cls] = v;
                rv[r] = (cls >= 1 && cls < C) ? v : -3e38f;
            }
            #pragma unroll
            for (int r = 0; r < 4; ++r) {
                float mv = rv[r]; int mi = cls;
                #pragma unroll
                for (int m = 1; m <= 8; m <<= 1) {
                    float ov = __shfl_xor(mv, m, 64);
                    int   oi = __shfl_xor(mi, m, 64);
                    if (ov > mv || (ov == mv && oi < mi)) { mv = ov; mi = oi; }
                }
                if (lr == 0) { smax[lq * 4 + r][nt] = mv; simax[lq * 4 + r][nt] = mi; }
            }
        }
    }
    __syncthreads();
    if (tid < 16) {
        float bv = -3e38f; int bx = 1 << 20;
        #pragma unroll
        for (int p = 0; p < 10; ++p) {
            float v = smax[tid][p]; int ix = simax[tid][p];
            if (v > bv || (v == bv && ix < bx)) { bv = v; bx = ix; }
        }
        int lt = labels[t * B + m0 + tid];
        int cm = (lt == 0) ? bx : lt;
        comms[(size_t)t * B + m0 + tid] = (float)cm;
        eidx[m0 + tid] = cm + 1;
    }
    __syncthreads();
}

// ================= one dispatch per step: 72 blocks x 256 =================
// bids 0..63 : full-K h(t-1)@Ws (fp16x3, BK=64 as two 32-panels) fused with gate.
// bids 64..71: pred(t-1) -> dists/comms/eidx, then flag eReady[t].
// Gate phase (after GEMM) waits eReady[t]==8 (t>=1). 72 <= 256 CUs => co-resident.
__global__ __launch_bounds__(256) void step_kernel(
    const _Float16* __restrict__ hPhi, const _Float16* __restrict__ hPlo,
    _Float16* __restrict__ hOhi, _Float16* __restrict__ hOlo,
    const _Float16* __restrict__ WsThi, const _Float16* __restrict__ WsTlo,
    const _Float16* __restrict__ WoThi, const _Float16* __restrict__ WoTlo,
    const float* __restrict__ P, const float* __restrict__ Etab,
    const float* __restrict__ bs, const float* __restrict__ bo,
    const int* __restrict__ labels,
    float* __restrict__ c, int* __restrict__ eidx, int* __restrict__ eReady,
    float* __restrict__ dists, float* __restrict__ comms, int t)
{
    const int bid = blockIdx.x;
    const int tid = threadIdx.x;
    const int lane = tid & 63, w = tid >> 6;
    const int lr = lane & 15, lq = lane >> 4;

    __shared__ __align__(16) _Float16 sAh[2 * 4096];   // 16 KB: [panel][row128][32]
    __shared__ __align__(16) _Float16 sAl[2 * 4096];
    __shared__ __align__(16) _Float16 sBh[2 * 2560];   // 10 KB: [panel][brow80][32]
    __shared__ __align__(16) _Float16 sBl[2 * 2560];
    __shared__ float smax[16][10];
    __shared__ int   simax[16][10];

    if (bid >= 64) {
        // ---------------- pred block: pred(t-1) ----------------
        if (t >= 1) {
            pred_step(t - 1, (bid - 64) * 16, hPhi, hPlo, WoThi, WoTlo, bo, labels,
                      dists, comms, eidx, smax, simax);
            if (tid == 0) {
                __threadfence();
                atomicAdd(&eReady[t], 1);
            }
        }
        return;
    }

    // ---------------- GEMM block: ps slice for nt = bid ----------------
    const int nt = bid, n0 = nt * 16;
    f32x4 acc[2][5];
    #pragma unroll
    for (int i = 0; i < 2; ++i)
        #pragma unroll
        for (int g = 0; g < 5; ++g)
            acc[i][g] = (f32x4){0.f, 0.f, 0.f, 0.f};

    if (t >= 1) {
        for (int r = 0; r < 16; ++r) {
            const int k0 = r * 64;
            #pragma unroll
            for (int p = 0; p < 2; ++p) {
                const int kp = k0 + p * 32;
                #pragma unroll
                for (int i = 0; i < 2; ++i) {
                    int s = i * 256 + tid;          // 0..511
                    int row = s >> 2, kc = s & 3;   // row 0..127
                    size_t ga = (size_t)row * H + kp + kc * 8;
                    int loff = p * 4096 + s * 8;
                    GLOAD_LDS16(hPhi + ga, sAh + loff);
                    GLOAD_LDS16(hPlo + ga, sAl + loff);
                }
                #pragma unroll
                for (int i = 0; i < 2; ++i) {
                    int s = i * 256 + tid;
                    if (s < 320) {                  // wave-uniform guard
                        int brow = s >> 2, kc = s & 3;   // brow 0..79
                        size_t gb = (size_t)((brow >> 4) * H + n0 + (brow & 15)) * H
                                    + kp + kc * 8;
                        int loff = p * 2560 + s * 8;
                        GLOAD_LDS16(WsThi + gb, sBh + loff);
                        GLOAD_LDS16(WsTlo + gb, sBl + loff);
                    }
                }
            }
            __syncthreads();
            #pragma unroll
            for (int p = 0; p < 2; ++p) {
                f16x8 ah[2], al[2];
                #pragma unroll
                for (int i = 0; i < 2; ++i) {
                    ah[i] = *(const f16x8*)&sAh[p * 4096 + ((w * 2 + i) * 16 + lr) * 32 + lq * 8];
                    al[i] = *(const f16x8*)&sAl[p * 4096 + ((w * 2 + i) * 16 + lr) * 32 + lq * 8];
                }
                #pragma unroll
                for (int g = 0; g < 5; ++g) {
                    f16x8 bh = *(const f16x8*)&sBh[p * 2560 + (g * 16 + lr) * 32 + lq * 8];
                    f16x8 bl = *(const f16x8*)&sBl[p * 2560 + (g * 16 + lr) * 32 + lq * 8];
                    #pragma unroll
                    for (int i = 0; i < 2; ++i) {
                        acc[i][g] = MFMA16(ah[i], bh, acc[i][g]);
                        acc[i][g] = MFMA16(ah[i], bl, acc[i][g]);
                        acc[i][g] = MFMA16(al[i], bh, acc[i][g]);
                    }
                }
            }
            __syncthreads();
        }
        // wait for eidx(t-1) from the 8 pred blocks (usually already done)
        if (tid == 0) wait_ge(&eReady[t], 8);
        __syncthreads();
    }

    // ---------------- gate epilogue: writes h(t), c(t) ----------------
    #pragma unroll
    for (int i = 0; i < 2; ++i)
        #pragma unroll
        for (int r = 0; r < 4; ++r) {
            int bb = (w * 2 + i) * 16 + lq * 4 + r;
            int j = n0 + lr;
            int e = (t >= 1) ? eidx[bb] : 0;
            size_t pbase = ((size_t)t * B + bb) * SIXH + j;
            size_t ebase = (size_t)e * SIXH + j;
            float gv[5];
            #pragma unroll
            for (int g = 0; g < 5; ++g)
                gv[g] = acc[i][g][r] + P[pbase + g * 1024]
                        + Etab[ebase + g * 1024] + bs[g * 1024 + j];
            float p5 = P[pbase + 5 * 1024] + Etab[ebase + 5 * 1024];
            float ig  = sigm(gv[0]);
            float fg  = sigm(gv[1]);
            float mi_ = tanhf(gv[2]);
            float og  = sigm(gv[3]);
            float hw  = sigm(gv[4]);
            float cv  = (t >= 1) ? c[(size_t)bb * H + j] : 0.f;
            float cn  = ig * mi_ + fg * cv;
            float out = og * tanhf(cn);
            float hn  = hw * out + (1.f - hw) * p5;
            c[(size_t)bb * H + j] = cn;
            _Float16 hh = (_Float16)hn;
            hOhi[(size_t)bb * H + j] = hh;
            hOlo[(size_t)bb * H + j] = (_Float16)(hn - (float)hh);
        }
}

// ---------------- trailing pred for t = T-1 ----------------
__global__ __launch_bounds__(256) void pred_kernel8(
    const _Float16* __restrict__ hhi, const _Float16* __restrict__ hlo,
    const _Float16* __restrict__ WoThi, const _Float16* __restrict__ WoTlo,
    const float* __restrict__ bo, const int* __restrict__ labels,
    float* __restrict__ dists, float* __restrict__ comms,
    int* __restrict__ eidx, int t)
{
    __shared__ float smax[16][10];
    __shared__ int   simax[16][10];
    pred_step(t, blockIdx.x * 16, hhi, hlo, WoThi, WoTlo, bo, labels,
              dists, comms, eidx, smax, simax);
}

extern "C" void kernel_launch(void* const* d_in, const int* in_sizes, int n_in,
                              void* d_out, int out_size, void* d_ws, size_t ws_size,
                              hipStream_t stream) {
    const float* X      = (const float*)d_in[0];
    const int*   labels = (const int*)  d_in[1];
    const float* embed  = (const float*)d_in[2];
    const float* Wi     = (const float*)d_in[3];
    const float* bi     = (const float*)d_in[4];
    const float* Ws     = (const float*)d_in[5];
    const float* bs     = (const float*)d_in[6];
    const float* Wo     = (const float*)d_in[7];
    const float* bo     = (const float*)d_in[8];

    char* w = (char*)d_ws;
    float* P        = (float*)w;    w += (size_t)T * B * SIXH * 4;      // 100.7 MB
    float* Etab     = (float*)w;    w += (size_t)NEMB * SIXH * 4;       //   3.7 MB
    _Float16* Xhi   = (_Float16*)w; w += (size_t)T * B * KTOT * 2;      //  16.8 MB
    _Float16* Xlo   = (_Float16*)w; w += (size_t)T * B * KTOT * 2;      //  16.8 MB
    char* overlay   = w;
    _Float16* WiThi = (_Float16*)w; w += (size_t)SIXH * KTOT * 2;       //  25.2 MB
    _Float16* WiTlo = (_Float16*)w; w += (size_t)SIXH * KTOT * 2;       //  25.2 MB

    // overlay region (live only after big_gemm; ~24 MB < 50.3 MB)
    char* r = overlay;
    _Float16* WsThi = (_Float16*)r; r += (size_t)FIVEH * H * 2;         //  10.5 MB
    _Float16* WsTlo = (_Float16*)r; r += (size_t)FIVEH * H * 2;         //  10.5 MB
    _Float16* WoThi = (_Float16*)r; r += (size_t)160 * H * 2;
    _Float16* WoTlo = (_Float16*)r; r += (size_t)160 * H * 2;
    _Float16* hhi0  = (_Float16*)r; r += (size_t)B * H * 2;
    _Float16* hlo0  = (_Float16*)r; r += (size_t)B * H * 2;
    _Float16* hhi1  = (_Float16*)r; r += (size_t)B * H * 2;
    _Float16* hlo1  = (_Float16*)r; r += (size_t)B * H * 2;
    float* cArr     = (float*)r;    r += (size_t)B * H * 4;
    int*   eidx     = (int*)r;      r += 512;
    int*   eReady   = (int*)r;      r += T * 4;

    float* dists = (float*)d_out;
    float* comms = dists + (size_t)T * B * C;

    cvt_x<<<(T * B * KTOT) / (256 * 4), 256, 0, stream>>>(X, Xhi, Xlo);
    cvt_wT<KTOT, SIXH><<<dim3(SIXH / 32, KTOT / 32), 256, 0, stream>>>(Wi, WiThi, WiTlo);
    etab_kernel<<<dim3(SIXH / 256, NEMB), 256, 0, stream>>>(embed, Wi, Etab);
    big_gemm_mfma<<<dim3(SIXH / 128, (T * B) / 128), 256, 0, stream>>>(Xhi, Xlo, WiThi, WiTlo, bi, P);
    cvt_wT<H, FIVEH><<<dim3(FIVEH / 32, H / 32), 256, 0, stream>>>(Ws, WsThi, WsTlo);
    cvt_woT<<<(160 * H) / 256, 256, 0, stream>>>(Wo, WoThi, WoTlo);
    hipMemsetAsync(eReady, 0, T * 4, stream);

    for (int t = 0; t < T; ++t) {
        const _Float16 *rdHi, *rdLo;
        _Float16 *wrHi, *wrLo;
        if (t & 1) { rdHi = hhi0; rdLo = hlo0; wrHi = hhi1; wrLo = hlo1; }
        else       { rdHi = hhi1; rdLo = hlo1; wrHi = hhi0; wrLo = hlo0; }
        step_kernel<<<72, 256, 0, stream>>>(rdHi, rdLo, wrHi, wrLo,
                                            WsThi, WsTlo, WoThi, WoTlo,
                                            P, Etab, bs, bo, labels,
                                            cArr, eidx, eReady, dists, comms, t);
    }
    // pred for the final step's h (t = T-1 is odd -> h in hhi1/hlo1)
    pred_kernel8<<<8, 256, 0, stream>>>(hhi1, hlo1, WoThi, WoTlo, bo, labels,
                                        dists, comms, eidx, T - 1);
}